// Round 1
// baseline (1147.693 us; speedup 1.0000x reference)
//
#include <hip/hip_runtime.h>
#include <hip/hip_bf16.h>
#include <stdint.h>

typedef __bf16 bf16;
typedef __bf16 bf16x8 __attribute__((ext_vector_type(8)));
typedef __bf16 bf16x4 __attribute__((ext_vector_type(4)));
typedef float  floatx4 __attribute__((ext_vector_type(4)));

#define DIMD 2048
#define BATB 4
#define SEQS 4096
#define MTOT (BATB*SEQS)   // 16384

__device__ __forceinline__ void gload_lds16(const bf16* g, bf16* l) {
    __builtin_amdgcn_global_load_lds(
        (const __attribute__((address_space(1))) void*)g,
        (__attribute__((address_space(3))) void*)l,
        16, 0, 0);
}

// ---------------- fp32 -> bf16 convert (weights) ----------------
__global__ __launch_bounds__(256) void f2bf_k(const float* __restrict__ src,
                                              bf16* __restrict__ dst, int n) {
    int i = (blockIdx.x * 256 + threadIdx.x) * 4;
    if (i >= n) return;
    float4 v = *(const float4*)&src[i];
    bf16x4 o;
    o[0] = (bf16)v.x; o[1] = (bf16)v.y; o[2] = (bf16)v.z; o[3] = (bf16)v.w;
    *(bf16x4*)&dst[i] = o;
}

// ---------------- RMSNorm: fp32 [M,2048] -> bf16 [M,2048] ----------------
__global__ __launch_bounds__(256) void rmsnorm_k(const float* __restrict__ x,
                                                 bf16* __restrict__ xn) {
    const int row = blockIdx.x;
    const int tid = threadIdx.x;
    const float* xr = x + (size_t)row * DIMD;
    float4 a = *(const float4*)&xr[tid * 8];
    float4 b = *(const float4*)&xr[tid * 8 + 4];
    float s = a.x*a.x + a.y*a.y + a.z*a.z + a.w*a.w
            + b.x*b.x + b.y*b.y + b.z*b.z + b.w*b.w;
    #pragma unroll
    for (int off = 32; off > 0; off >>= 1) s += __shfl_down(s, off);
    __shared__ float red[4];
    if ((tid & 63) == 0) red[tid >> 6] = s;
    __syncthreads();
    float tot = red[0] + red[1] + red[2] + red[3];
    float sc = rsqrtf(tot * (1.0f / DIMD) + 1.1920929e-07f);
    bf16x8 o;
    o[0] = (bf16)(a.x * sc); o[1] = (bf16)(a.y * sc);
    o[2] = (bf16)(a.z * sc); o[3] = (bf16)(a.w * sc);
    o[4] = (bf16)(b.x * sc); o[5] = (bf16)(b.y * sc);
    o[6] = (bf16)(b.z * sc); o[7] = (bf16)(b.w * sc);
    *(bf16x8*)&xn[(size_t)row * DIMD + tid * 8] = o;
}

// ---------------- gating + causal depthwise conv ----------------
// h layout per row m: [B_gate(0..D) | C_gate(D..2D) | z(2D..3D)], bf16
// y = B*z ; conv: out[s] = w0*y[s-2*dil] + w1*y[s-dil] + w2*y[s] + cb ; o = C*out
__global__ __launch_bounds__(256) void gateconv_k(const bf16* __restrict__ h,
                                                  const float* __restrict__ cw,
                                                  const float* __restrict__ cb,
                                                  bf16* __restrict__ o,
                                                  const int* __restrict__ dil_p) {
    int gid = blockIdx.x * 256 + threadIdx.x;
    int m = gid >> 9;            // 512 groups of 4 dims per row
    int d = (gid & 511) << 2;
    int s = m & (SEQS - 1);
    int dil = dil_p[0];
    const bf16* hr = h + (size_t)m * (3 * DIMD);

    bf16x4 Cv = *(const bf16x4*)&hr[DIMD + d];
    bf16x4 B0 = *(const bf16x4*)&hr[d];
    bf16x4 Z0 = *(const bf16x4*)&hr[2 * DIMD + d];
    float y0[4], y1[4], y2[4];
    #pragma unroll
    for (int j = 0; j < 4; ++j) y0[j] = (float)B0[j] * (float)Z0[j];
    if (s >= dil) {
        const bf16* h1 = hr - (size_t)dil * 3 * DIMD;
        bf16x4 B1 = *(const bf16x4*)&h1[d];
        bf16x4 Z1 = *(const bf16x4*)&h1[2 * DIMD + d];
        #pragma unroll
        for (int j = 0; j < 4; ++j) y1[j] = (float)B1[j] * (float)Z1[j];
    } else {
        #pragma unroll
        for (int j = 0; j < 4; ++j) y1[j] = 0.0f;
    }
    if (s >= 2 * dil) {
        const bf16* h2 = hr - (size_t)(2 * dil) * 3 * DIMD;
        bf16x4 B2 = *(const bf16x4*)&h2[d];
        bf16x4 Z2 = *(const bf16x4*)&h2[2 * DIMD + d];
        #pragma unroll
        for (int j = 0; j < 4; ++j) y2[j] = (float)B2[j] * (float)Z2[j];
    } else {
        #pragma unroll
        for (int j = 0; j < 4; ++j) y2[j] = 0.0f;
    }
    bf16x4 ov;
    #pragma unroll
    for (int j = 0; j < 4; ++j) {
        float w0 = cw[(d + j) * 3 + 0];
        float w1 = cw[(d + j) * 3 + 1];
        float w2 = cw[(d + j) * 3 + 2];
        float conv = w0 * y2[j] + w1 * y1[j] + w2 * y0[j] + cb[d + j];
        ov[j] = (bf16)((float)Cv[j] * conv);
    }
    *(bf16x4*)&o[(size_t)m * DIMD + d] = ov;
}

// ---------------- NT bf16 GEMM: C[M,N] = A[M,K] * B[N,K]^T ----------------
// m97-style: 128x128 tile, BK=64, 4 waves, each wave 64x64 via 4x4 16x16x32 MFMAs,
// global_load_lds width-16 staging.
template<int RESID>
__global__ __launch_bounds__(256) void gemm_bt(const bf16* __restrict__ A,
                                               const bf16* __restrict__ B,
                                               bf16* __restrict__ Hout,
                                               float* __restrict__ Fout,
                                               const float* __restrict__ resid,
                                               const float* __restrict__ scale,
                                               int M, int N, int K) {
    constexpr int BM = 128, BN = 128, BK = 64;
    __shared__ __align__(16) bf16 As[BM * BK];
    __shared__ __align__(16) bf16 Bs[BN * BK];
    const int tid = threadIdx.x;
    const int wave = tid >> 6;
    const int lane = tid & 63;
    const int quad = lane >> 4;
    const int col16 = lane & 15;
    const int m0 = blockIdx.y * BM;
    const int n0 = blockIdx.x * BN;
    const int wm = (wave >> 1) * 64;
    const int wn = (wave & 1) * 64;

    // staging: 4 calls per thread per operand; call j covers LDS bytes
    // [(j*256+wave*64)*16 .. +1024) = 8 rows of the [128][64] bf16 tile
    const bf16* aptr[4];
    const bf16* bptr[4];
    bf16* alds[4];
    bf16* blds[4];
    #pragma unroll
    for (int j = 0; j < 4; ++j) {
        int idx = j * 256 + wave * 64 + lane;
        int row = idx >> 3;
        int ck = (idx & 7) * 8;
        aptr[j] = A + (size_t)(m0 + row) * K + ck;
        bptr[j] = B + (size_t)(n0 + row) * K + ck;
        int ubase = (j * 256 + wave * 64) * 8;  // wave-uniform (per-wave) element base
        alds[j] = As + ubase;
        blds[j] = Bs + ubase;
    }

    floatx4 acc[4][4];
    #pragma unroll
    for (int i = 0; i < 4; ++i)
        #pragma unroll
        for (int j = 0; j < 4; ++j) acc[i][j] = (floatx4)0.0f;

    for (int k0 = 0; k0 < K; k0 += BK) {
        #pragma unroll
        for (int j = 0; j < 4; ++j) gload_lds16(aptr[j] + k0, alds[j]);
        #pragma unroll
        for (int j = 0; j < 4; ++j) gload_lds16(bptr[j] + k0, blds[j]);
        __syncthreads();
        #pragma unroll
        for (int kk = 0; kk < BK; kk += 32) {
            bf16x8 af[4], bfr[4];
            #pragma unroll
            for (int mi = 0; mi < 4; ++mi)
                af[mi] = *(const bf16x8*)&As[(wm + mi * 16 + col16) * BK + kk + quad * 8];
            #pragma unroll
            for (int ni = 0; ni < 4; ++ni)
                bfr[ni] = *(const bf16x8*)&Bs[(wn + ni * 16 + col16) * BK + kk + quad * 8];
            #pragma unroll
            for (int mi = 0; mi < 4; ++mi)
                #pragma unroll
                for (int ni = 0; ni < 4; ++ni)
                    acc[mi][ni] = __builtin_amdgcn_mfma_f32_16x16x32_bf16(
                        af[mi], bfr[ni], acc[mi][ni], 0, 0, 0);
        }
        __syncthreads();
    }

    // epilogue: C/D map col=lane&15, row=quad*4+reg
    #pragma unroll
    for (int mi = 0; mi < 4; ++mi) {
        #pragma unroll
        for (int ni = 0; ni < 4; ++ni) {
            int c = n0 + wn + ni * 16 + col16;
            int rbase = m0 + wm + mi * 16 + quad * 4;
            #pragma unroll
            for (int r = 0; r < 4; ++r) {
                size_t off = (size_t)(rbase + r) * N + c;
                float v = acc[mi][ni][r];
                if (RESID) {
                    Fout[off] = resid[off] + scale[c] * v;
                } else {
                    Hout[off] = (bf16)v;
                }
            }
        }
    }
}

extern "C" void kernel_launch(void* const* d_in, const int* in_sizes, int n_in,
                              void* d_out, int out_size, void* d_ws, size_t ws_size,
                              hipStream_t stream) {
    const float* x  = (const float*)d_in[0];
    const float* We = (const float*)d_in[1];
    const float* cw = (const float*)d_in[2];
    const float* cb = (const float*)d_in[3];
    const float* Wp = (const float*)d_in[4];
    const float* cs = (const float*)d_in[5];
    const int*   dil = (const int*)d_in[6];

    char* ws = (char*)d_ws;
    bf16* xn  = (bf16*)ws;                                  // 67108864 B (reused for o)
    bf16* Web = (bf16*)(ws + 67108864);                     // 25165824 B
    bf16* Wpb = (bf16*)(ws + 67108864 + 25165824);          // 8388608 B
    bf16* h   = (bf16*)(ws + 100663296);                    // 201326592 B
    // total ws use: 301,989,888 B

    f2bf_k<<<(3 * DIMD * DIMD / 4 + 255) / 256, 256, 0, stream>>>(We, Web, 3 * DIMD * DIMD);
    f2bf_k<<<(DIMD * DIMD / 4 + 255) / 256, 256, 0, stream>>>(Wp, Wpb, DIMD * DIMD);
    rmsnorm_k<<<MTOT, 256, 0, stream>>>(x, xn);
    gemm_bt<0><<<dim3(3 * DIMD / 128, MTOT / 128), 256, 0, stream>>>(
        xn, Web, h, nullptr, nullptr, nullptr, MTOT, 3 * DIMD, DIMD);
    gateconv_k<<<(MTOT * (DIMD / 4)) / 256, 256, 0, stream>>>(h, cw, cb, xn /*o*/, dil);
    gemm_bt<1><<<dim3(DIMD / 128, MTOT / 128), 256, 0, stream>>>(
        xn /*o*/, Wpb, nullptr, (float*)d_out, x, cs, MTOT, DIMD, DIMD);
}

// Round 2
// 973.215 us; speedup vs baseline: 1.1793x; 1.1793x over previous
//
#include <hip/hip_runtime.h>
#include <hip/hip_bf16.h>
#include <stdint.h>

typedef __bf16 bf16;
typedef __bf16 bf16x8 __attribute__((ext_vector_type(8)));
typedef __bf16 bf16x4 __attribute__((ext_vector_type(4)));
typedef float  floatx4 __attribute__((ext_vector_type(4)));

#define DIMD 2048
#define BATB 4
#define SEQS 4096
#define MTOT (BATB*SEQS)   // 16384

__device__ __forceinline__ void gload_lds16(const bf16* g, bf16* l) {
    __builtin_amdgcn_global_load_lds(
        (const __attribute__((address_space(1))) void*)g,
        (__attribute__((address_space(3))) void*)l,
        16, 0, 0);
}

// ---------------- fp32 -> bf16 convert (weights) ----------------
__global__ __launch_bounds__(256) void f2bf_k(const float* __restrict__ src,
                                              bf16* __restrict__ dst, int n) {
    int i = (blockIdx.x * 256 + threadIdx.x) * 4;
    if (i >= n) return;
    float4 v = *(const float4*)&src[i];
    bf16x4 o;
    o[0] = (bf16)v.x; o[1] = (bf16)v.y; o[2] = (bf16)v.z; o[3] = (bf16)v.w;
    *(bf16x4*)&dst[i] = o;
}

// ---------------- RMSNorm: fp32 [M,2048] -> bf16 [M,2048] ----------------
__global__ __launch_bounds__(256) void rmsnorm_k(const float* __restrict__ x,
                                                 bf16* __restrict__ xn) {
    const int row = blockIdx.x;
    const int tid = threadIdx.x;
    const float* xr = x + (size_t)row * DIMD;
    float4 a = *(const float4*)&xr[tid * 8];
    float4 b = *(const float4*)&xr[tid * 8 + 4];
    float s = a.x*a.x + a.y*a.y + a.z*a.z + a.w*a.w
            + b.x*b.x + b.y*b.y + b.z*b.z + b.w*b.w;
    #pragma unroll
    for (int off = 32; off > 0; off >>= 1) s += __shfl_down(s, off);
    __shared__ float red[4];
    if ((tid & 63) == 0) red[tid >> 6] = s;
    __syncthreads();
    float tot = red[0] + red[1] + red[2] + red[3];
    float sc = rsqrtf(tot * (1.0f / DIMD) + 1.1920929e-07f);
    bf16x8 o;
    o[0] = (bf16)(a.x * sc); o[1] = (bf16)(a.y * sc);
    o[2] = (bf16)(a.z * sc); o[3] = (bf16)(a.w * sc);
    o[4] = (bf16)(b.x * sc); o[5] = (bf16)(b.y * sc);
    o[6] = (bf16)(b.z * sc); o[7] = (bf16)(b.w * sc);
    *(bf16x8*)&xn[(size_t)row * DIMD + tid * 8] = o;
}

// ---------------- gating + causal depthwise conv ----------------
__global__ __launch_bounds__(256) void gateconv_k(const bf16* __restrict__ h,
                                                  const float* __restrict__ cw,
                                                  const float* __restrict__ cb,
                                                  bf16* __restrict__ o,
                                                  const int* __restrict__ dil_p) {
    int gid = blockIdx.x * 256 + threadIdx.x;
    int m = gid >> 9;            // 512 groups of 4 dims per row
    int d = (gid & 511) << 2;
    int s = m & (SEQS - 1);
    int dil = dil_p[0];
    const bf16* hr = h + (size_t)m * (3 * DIMD);

    bf16x4 Cv = *(const bf16x4*)&hr[DIMD + d];
    bf16x4 B0 = *(const bf16x4*)&hr[d];
    bf16x4 Z0 = *(const bf16x4*)&hr[2 * DIMD + d];
    float y0[4], y1[4], y2[4];
    #pragma unroll
    for (int j = 0; j < 4; ++j) y0[j] = (float)B0[j] * (float)Z0[j];
    if (s >= dil) {
        const bf16* h1 = hr - (size_t)dil * 3 * DIMD;
        bf16x4 B1 = *(const bf16x4*)&h1[d];
        bf16x4 Z1 = *(const bf16x4*)&h1[2 * DIMD + d];
        #pragma unroll
        for (int j = 0; j < 4; ++j) y1[j] = (float)B1[j] * (float)Z1[j];
    } else {
        #pragma unroll
        for (int j = 0; j < 4; ++j) y1[j] = 0.0f;
    }
    if (s >= 2 * dil) {
        const bf16* h2 = hr - (size_t)(2 * dil) * 3 * DIMD;
        bf16x4 B2 = *(const bf16x4*)&h2[d];
        bf16x4 Z2 = *(const bf16x4*)&h2[2 * DIMD + d];
        #pragma unroll
        for (int j = 0; j < 4; ++j) y2[j] = (float)B2[j] * (float)Z2[j];
    } else {
        #pragma unroll
        for (int j = 0; j < 4; ++j) y2[j] = 0.0f;
    }
    bf16x4 ov;
    #pragma unroll
    for (int j = 0; j < 4; ++j) {
        float w0 = cw[(d + j) * 3 + 0];
        float w1 = cw[(d + j) * 3 + 1];
        float w2 = cw[(d + j) * 3 + 2];
        float conv = w0 * y2[j] + w1 * y1[j] + w2 * y0[j] + cb[d + j];
        ov[j] = (bf16)((float)Cv[j] * conv);
    }
    *(bf16x4*)&o[(size_t)m * DIMD + d] = ov;
}

// ---------------- NT bf16 GEMM: C[M,N] = A[M,K] * B[N,K]^T ----------------
// 128x128 tile, BK=64, 4 waves, each wave 64x64 via 4x4 16x16x32 MFMAs.
// LDS layout XOR-swizzled: logical 16B chunk (row, c) stored at slot c^(row&7).
// Staging lane (row, c) therefore FETCHES global chunk c^(row&7) so that
// global_load_lds's fixed lane->LDS placement realizes the swizzle.
template<int RESID>
__global__ __launch_bounds__(256) void gemm_bt(const bf16* __restrict__ A,
                                               const bf16* __restrict__ B,
                                               bf16* __restrict__ Hout,
                                               float* __restrict__ Fout,
                                               const float* __restrict__ resid,
                                               const float* __restrict__ scale,
                                               int M, int N, int K) {
    constexpr int BM = 128, BN = 128, BK = 64;
    __shared__ __align__(16) bf16 As[BM * BK];
    __shared__ __align__(16) bf16 Bs[BN * BK];
    const int tid = threadIdx.x;
    const int wave = tid >> 6;
    const int lane = tid & 63;
    const int quad = lane >> 4;
    const int col16 = lane & 15;
    const int m0 = blockIdx.y * BM;
    const int n0 = blockIdx.x * BN;
    const int wm = (wave >> 1) * 64;
    const int wn = (wave & 1) * 64;

    const bf16* aptr[4];
    const bf16* bptr[4];
    bf16* alds[4];
    bf16* blds[4];
    #pragma unroll
    for (int j = 0; j < 4; ++j) {
        int idx = j * 256 + wave * 64 + lane;
        int row = idx >> 3;
        int ck = ((idx ^ row) & 7) * 8;  // swizzle: fetch chunk c^(row&7)
        aptr[j] = A + (size_t)(m0 + row) * K + ck;
        bptr[j] = B + (size_t)(n0 + row) * K + ck;
        int ubase = (j * 256 + wave * 64) * 8;  // wave-uniform element base
        alds[j] = As + ubase;
        blds[j] = Bs + ubase;
    }

    floatx4 acc[4][4];
    #pragma unroll
    for (int i = 0; i < 4; ++i)
        #pragma unroll
        for (int j = 0; j < 4; ++j) acc[i][j] = (floatx4)0.0f;

    const int rswiz = col16 & 7;   // = row&7 for every fragment row this lane touches

    for (int k0 = 0; k0 < K; k0 += BK) {
        #pragma unroll
        for (int j = 0; j < 4; ++j) gload_lds16(aptr[j] + k0, alds[j]);
        #pragma unroll
        for (int j = 0; j < 4; ++j) gload_lds16(bptr[j] + k0, blds[j]);
        __syncthreads();
        #pragma unroll
        for (int kk = 0; kk < BK; kk += 32) {
            // logical chunk = quad + (kk/32)*4; swizzled slot = chunk ^ rswiz
            const int slot = ((quad + (kk >> 5) * 4) ^ rswiz) * 8;
            bf16x8 af[4], bfr[4];
            #pragma unroll
            for (int mi = 0; mi < 4; ++mi)
                af[mi] = *(const bf16x8*)&As[(wm + mi * 16 + col16) * BK + slot];
            #pragma unroll
            for (int ni = 0; ni < 4; ++ni)
                bfr[ni] = *(const bf16x8*)&Bs[(wn + ni * 16 + col16) * BK + slot];
            #pragma unroll
            for (int mi = 0; mi < 4; ++mi)
                #pragma unroll
                for (int ni = 0; ni < 4; ++ni)
                    acc[mi][ni] = __builtin_amdgcn_mfma_f32_16x16x32_bf16(
                        af[mi], bfr[ni], acc[mi][ni], 0, 0, 0);
        }
        __syncthreads();
    }

    // epilogue: C/D map col=lane&15, row=quad*4+reg
    #pragma unroll
    for (int mi = 0; mi < 4; ++mi) {
        #pragma unroll
        for (int ni = 0; ni < 4; ++ni) {
            int c = n0 + wn + ni * 16 + col16;
            int rbase = m0 + wm + mi * 16 + quad * 4;
            #pragma unroll
            for (int r = 0; r < 4; ++r) {
                size_t off = (size_t)(rbase + r) * N + c;
                float v = acc[mi][ni][r];
                if (RESID) {
                    Fout[off] = resid[off] + scale[c] * v;
                } else {
                    Hout[off] = (bf16)v;
                }
            }
        }
    }
}

extern "C" void kernel_launch(void* const* d_in, const int* in_sizes, int n_in,
                              void* d_out, int out_size, void* d_ws, size_t ws_size,
                              hipStream_t stream) {
    const float* x  = (const float*)d_in[0];
    const float* We = (const float*)d_in[1];
    const float* cw = (const float*)d_in[2];
    const float* cb = (const float*)d_in[3];
    const float* Wp = (const float*)d_in[4];
    const float* cs = (const float*)d_in[5];
    const int*   dil = (const int*)d_in[6];

    char* ws = (char*)d_ws;
    bf16* xn  = (bf16*)ws;                                  // 67108864 B (reused for o)
    bf16* Web = (bf16*)(ws + 67108864);                     // 25165824 B
    bf16* Wpb = (bf16*)(ws + 67108864 + 25165824);          // 8388608 B
    bf16* h   = (bf16*)(ws + 100663296);                    // 201326592 B

    f2bf_k<<<(3 * DIMD * DIMD / 4 + 255) / 256, 256, 0, stream>>>(We, Web, 3 * DIMD * DIMD);
    f2bf_k<<<(DIMD * DIMD / 4 + 255) / 256, 256, 0, stream>>>(Wp, Wpb, DIMD * DIMD);
    rmsnorm_k<<<MTOT, 256, 0, stream>>>(x, xn);
    gemm_bt<0><<<dim3(3 * DIMD / 128, MTOT / 128), 256, 0, stream>>>(
        xn, Web, h, nullptr, nullptr, nullptr, MTOT, 3 * DIMD, DIMD);
    gateconv_k<<<(MTOT * (DIMD / 4)) / 256, 256, 0, stream>>>(h, cw, cb, xn /*o*/, dil);
    gemm_bt<1><<<dim3(DIMD / 128, MTOT / 128), 256, 0, stream>>>(
        xn /*o*/, Wpb, nullptr, (float*)d_out, x, cs, MTOT, DIMD, DIMD);
}